// Round 16
// baseline (669.706 us; speedup 1.0000x reference)
//
#include <hip/hip_runtime.h>
#include <math.h>

typedef __attribute__((ext_vector_type(8))) short bf16x8;
typedef __attribute__((ext_vector_type(4))) float f32x4;
typedef unsigned short u16;
typedef __attribute__((ext_vector_type(4))) unsigned short u16x4;
typedef __attribute__((ext_vector_type(8))) unsigned short u16x8;
typedef __attribute__((ext_vector_type(4))) unsigned int u32x4;

#define VN_EPS 1e-6f
#define LN_EPS 1e-5f
#define BN_EPS 1e-5f
#define ISQ 0.10206207261596575f

__device__ __forceinline__ u16 f2bf(float f) {
    unsigned u = __builtin_bit_cast(unsigned, f);
    return (u16)((u + 0x7FFFu + ((u >> 16) & 1u)) >> 16);
}
__device__ __forceinline__ float bf2f(u16 h) {
    unsigned u = ((unsigned)h) << 16;
    return __builtin_bit_cast(float, u);
}

// ---------------------------------------------------------------- u = eps*b/||b||
__global__ __launch_bounds__(256) void k_u(
    const float* __restrict__ b0, const float* __restrict__ b1,
    const float* __restrict__ b2, const float* __restrict__ b3,
    const float* __restrict__ b4, const float* __restrict__ b5,
    float* __restrict__ uall)
{
    const float* bs[6] = {b0, b1, b2, b3, b4, b5};
    const float* bp = bs[blockIdx.x];
    const int co = threadIdx.x;
    const float v0 = bp[co*3+0], v1 = bp[co*3+1], v2 = bp[co*3+2];
    const float inv = rsqrtf(v0*v0 + v1*v1 + v2*v2);
    float* u = uall + blockIdx.x*768 + co*3;
    u[0] = VN_EPS*v0*inv; u[1] = VN_EPS*v1*inv; u[2] = VN_EPS*v2*inv;
}

// ---------------------------------------------------------------- W f32 [i][o] -> Wt hi/lo bf16 [o][i]
__global__ __launch_bounds__(256) void k_wtrans(
    const float* __restrict__ w0, const float* __restrict__ w1,
    const float* __restrict__ w2, const float* __restrict__ w3,
    const float* __restrict__ w4, const float* __restrict__ w5,
    const float* __restrict__ w6, u16* __restrict__ wth, u16* __restrict__ wtl)
{
    const int wi = blockIdx.z;
    const float* W = (wi==0)?w0:(wi==1)?w1:(wi==2)?w2:(wi==3)?w3:(wi==4)?w4:(wi==5)?w5:w6;
    u16* WtH = wth + (long)wi*65536;
    u16* WtL = wtl + (long)wi*65536;
    const int i0 = blockIdx.y*64, o0 = blockIdx.x*64;
    __shared__ float st[64][67];
    const int t = threadIdx.x, q = t >> 6, lane = t & 63;
    for (int j = 0; j < 16; ++j) {
        const int i = q*16 + j;
        st[i][lane] = W[(i0 + i)*256 + o0 + lane];
    }
    __syncthreads();
    for (int j = 0; j < 16; ++j) {
        const int o = q*16 + j;
        const float v = st[lane][o];
        const u16 hi = f2bf(v);
        WtH[(o0 + o)*256 + i0 + lane] = hi;
        WtL[(o0 + o)*256 + i0 + lane] = f2bf(v - bf2f(hi));
    }
}

// ---------------------------------------------------------------- split-bf16 channel GEMM
// MODE 0: f32 original layout.
// MODE 1: z interleaved [row=b*768+co*3+d][n/8][hi8|lo8] (row=2048 u16).
// MODE 2: q/k interleaved head-major [bh][n][fblock 12][hi8|lo8] (row=192 u16).
template<int MODE>
__global__ __launch_bounds__(256) void k_cgemm(
    const float* __restrict__ X, const u16* __restrict__ WtH, const u16* __restrict__ WtL,
    const float* __restrict__ U,
    float* __restrict__ OutF, u16* __restrict__ OutI)
{
    __shared__ u16 sh[32768];
    const int tid = threadIdx.x;
    const int b = blockIdx.z / 3, d = blockIdx.z % 3;
    const int n0 = blockIdx.x * 64;
    const int co0 = blockIdx.y * 64;

    {
        const int tn = (tid & 15) * 4;
        const int ti = (tid >> 4) * 4;
        #pragma unroll
        for (int it = 0; it < 4; ++it) {
            const int i_l = it*64 + ti;
            const long rb = (((long)(b*256 + i_l))*3 + d)*1024 + n0 + tn;
            const float4 r0 = *(const float4*)&X[rb];
            const float4 r1 = *(const float4*)&X[rb + 3072];
            const float4 r2 = *(const float4*)&X[rb + 6144];
            const float4 r3 = *(const float4*)&X[rb + 9216];
            const float vals[4][4] = {
                {r0.x, r1.x, r2.x, r3.x},
                {r0.y, r1.y, r2.y, r3.y},
                {r0.z, r1.z, r2.z, r3.z},
                {r0.w, r1.w, r2.w, r3.w}};
            #pragma unroll
            for (int j = 0; j < 4; ++j) {
                const int n = tn + j;
                u16x4 hv, lv;
                #pragma unroll
                for (int e = 0; e < 4; ++e) {
                    const float v = vals[j][e];
                    const u16 hi = f2bf(v);
                    hv[e] = hi;
                    lv[e] = f2bf(v - bf2f(hi));
                }
                const int slot = i_l >> 3;
                const int idx = n*256 + ((((slot ^ (n & 7)) << 3)) | (i_l & 4));
                *(u16x4*)&sh[idx] = hv;
                *(u16x4*)&sh[16384 + idx] = lv;
            }
        }
    }
    __syncthreads();

    const int w = tid >> 6, l = tid & 63;
    const int lr = l & 15, lg = l >> 4;

    f32x4 zero = {0.f, 0.f, 0.f, 0.f};
    f32x4 acc[4] = {zero, zero, zero, zero};

    const long arow = (long)(co0 + w*16 + lr)*256 + lg*8;
    #pragma unroll
    for (int s = 0; s < 8; ++s) {
        const bf16x8 ah = *(const bf16x8*)(WtH + arow + s*32);
        const bf16x8 al = *(const bf16x8*)(WtL + arow + s*32);
        #pragma unroll
        for (int ni = 0; ni < 4; ++ni) {
            const int row = ni*16 + lr;
            const int slot = s*4 + lg;
            const int idx = row*256 + ((slot ^ (row & 7)) << 3);
            const bf16x8 bh_ = *(const bf16x8*)&sh[idx];
            const bf16x8 bl_ = *(const bf16x8*)&sh[16384 + idx];
            acc[ni] = __builtin_amdgcn_mfma_f32_16x16x32_bf16(ah, bh_, acc[ni], 0, 0, 0);
            acc[ni] = __builtin_amdgcn_mfma_f32_16x16x32_bf16(ah, bl_, acc[ni], 0, 0, 0);
            acc[ni] = __builtin_amdgcn_mfma_f32_16x16x32_bf16(al, bh_, acc[ni], 0, 0, 0);
        }
    }

    if constexpr (MODE == 0) {
        #pragma unroll
        for (int ni = 0; ni < 4; ++ni)
            #pragma unroll
            for (int r = 0; r < 4; ++r) {
                const int co = co0 + w*16 + lg*4 + r;
                const int nn = n0 + ni*16 + lr;
                float v = acc[ni][r];
                if (U) v += U[co*3 + d];
                OutF[(((long)(b*256 + co))*3 + d)*1024 + nn] = v;
            }
    } else if constexpr (MODE == 1) {
        #pragma unroll
        for (int ni = 0; ni < 4; ++ni)
            #pragma unroll
            for (int r = 0; r < 4; ++r) {
                const int co = co0 + w*16 + lg*4 + r;
                const int nn = n0 + ni*16 + lr;
                float v = acc[ni][r] + U[co*3 + d];
                const u16 hi = f2bf(v);
                const long idx = (long)(b*768 + co*3 + d)*2048 + ((nn >> 3) << 4) + (nn & 7);
                OutI[idx]     = hi;
                OutI[idx + 8] = f2bf(v - bf2f(hi));
            }
    } else {
        __syncthreads();
        u16* olh = sh;
        u16* oll = sh + 8448;
        #pragma unroll
        for (int ni = 0; ni < 4; ++ni)
            #pragma unroll
            for (int r = 0; r < 4; ++r) {
                const int co_l = w*16 + lg*4 + r;
                float v = acc[ni][r] + U[(co0 + co_l)*3 + d];
                const u16 hi = f2bf(v);
                olh[co_l*66 + ni*16 + lr] = hi;
                oll[co_l*66 + ni*16 + lr] = f2bf(v - bf2f(hi));
            }
        __syncthreads();
        const int n_l = tid & 63, grp = tid >> 6;
        const int h = (co0 >> 5) + (grp >> 1);
        const int fb0 = d*4 + (grp & 1)*2;
        const long nbase = (long)(b*8 + h)*196608 + (long)(n0 + n_l)*192;
        u16x8 v0h, v1h, v0l, v1l;
        #pragma unroll
        for (int p = 0; p < 8; ++p) {
            v0h[p] = olh[(grp*16 + p)*66 + n_l];
            v1h[p] = olh[(grp*16 + 8 + p)*66 + n_l];
            v0l[p] = oll[(grp*16 + p)*66 + n_l];
            v1l[p] = oll[(grp*16 + 8 + p)*66 + n_l];
        }
        *(u16x8*)&OutI[nbase + fb0*16]          = v0h;
        *(u16x8*)&OutI[nbase + fb0*16 + 8]      = v0l;
        *(u16x8*)&OutI[nbase + (fb0 + 1)*16]     = v1h;
        *(u16x8*)&OutI[nbase + (fb0 + 1)*16 + 8] = v1l;
    }
}

// ---------------------------------------------------------------- fused attention (r15 structure, interleaved hi/lo loads)
__global__ __launch_bounds__(256) void k_attn(
    const u16* __restrict__ Qi, const u16* __restrict__ Ki,
    const u16* __restrict__ Zi, float* __restrict__ Ao)
{
    const int i = blockIdx.x;            // 0..4095
    const int xcd = i & 7;
    const int j = i >> 3;
    const int bh = xcd*8 + (j >> 6);
    const int mt = j & 63;
    const int b = bh >> 3, h = bh & 7;
    const int m0 = mt*16;
    const int tid = threadIdx.x;
    const int w = tid >> 6, l = tid & 63, lr = l & 15, lg = l >> 4;

    __shared__ float smx[4][16];
    __shared__ float ssum[4][16];
    __shared__ float inv16[16];
    __shared__ float outl[16*100];

    f32x4 zero = {0.f, 0.f, 0.f, 0.f};

    // Q B-frags: row m0+lr, fblock s*4+lg (hi at +0, lo at +8)
    const long qrow = (long)bh*196608 + (long)(m0 + lr)*192;
    bf16x8 qhf[3], qlf[3];
    #pragma unroll
    for (int s = 0; s < 3; ++s) {
        qhf[s] = *(const bf16x8*)(Qi + qrow + (s*4 + lg)*16);
        qlf[s] = *(const bf16x8*)(Qi + qrow + (s*4 + lg)*16 + 8);
    }

    // ---- phase 1: 16 swapped-QK^T tiles; S^T in registers (m=lr, n=t*16 + lg*4+r)
    f32x4 sc[16];
    const long kbase = (long)bh*196608 + (long)(w*256 + lr)*192;
    #pragma unroll
    for (int t = 0; t < 16; ++t) {
        const long kb = kbase + (long)t*3072;      // 16 rows * 192
        f32x4 a = zero;
        #pragma unroll
        for (int s = 0; s < 3; ++s) {
            const bf16x8 khf = *(const bf16x8*)(Ki + kb + (s*4 + lg)*16);
            const bf16x8 klf = *(const bf16x8*)(Ki + kb + (s*4 + lg)*16 + 8);
            a = __builtin_amdgcn_mfma_f32_16x16x32_bf16(khf, qhf[s], a, 0, 0, 0);
            a = __builtin_amdgcn_mfma_f32_16x16x32_bf16(khf, qlf[s], a, 0, 0, 0);
            a = __builtin_amdgcn_mfma_f32_16x16x32_bf16(klf, qhf[s], a, 0, 0, 0);
        }
        sc[t] = a;
    }

    // ---- phase 2: exact softmax per m-row (batched, P back into sc as f32)
    float mx = -1e30f;
    #pragma unroll
    for (int t = 0; t < 16; ++t)
        #pragma unroll
        for (int r = 0; r < 4; ++r)
            mx = fmaxf(mx, sc[t][r]);
    mx = fmaxf(mx, __shfl_xor(mx, 16));
    mx = fmaxf(mx, __shfl_xor(mx, 32));
    if (lg == 0) smx[w][lr] = mx;
    __syncthreads();
    mx = fmaxf(fmaxf(smx[0][lr], smx[1][lr]), fmaxf(smx[2][lr], smx[3][lr]));

    float sm = 0.f;
    #pragma unroll
    for (int t = 0; t < 16; ++t)
        #pragma unroll
        for (int r = 0; r < 4; ++r) {
            const float p = __expf((sc[t][r] - mx) * ISQ);
            sc[t][r] = p;
            sm += p;
        }
    sm += __shfl_xor(sm, 16);
    sm += __shfl_xor(sm, 32);
    if (lg == 0) ssum[w][lr] = sm;
    __syncthreads();
    if (tid < 16)
        inv16[tid] = 1.0f / (ssum[0][tid] + ssum[1][tid] + ssum[2][tid] + ssum[3][tid]);

    // ---- phase 3: per 32-n chunk, shfl-exchange P into K=32 A-frags, full-rate PV
    f32x4 acc2[6];
    #pragma unroll
    for (int f = 0; f < 6; ++f) acc2[f] = zero;
    const long zrow = (long)(b*768 + h*96);
    const int sAl = lr + ((lg & 1) << 5);
    const int sBl = sAl + 16;
    const bool hiT = (lg & 2) != 0;
    #pragma unroll
    for (int c = 0; c < 8; ++c) {
        const f32x4 pA = sc[2*c], pB = sc[2*c + 1];
        const u16 a0 = f2bf(pA[0]), a1 = f2bf(pA[1]), a2 = f2bf(pA[2]), a3 = f2bf(pA[3]);
        const u16 b0 = f2bf(pB[0]), b1 = f2bf(pB[1]), b2 = f2bf(pB[2]), b3 = f2bf(pB[3]);
        const unsigned ah01 = (unsigned)a0 | ((unsigned)a1 << 16);
        const unsigned ah23 = (unsigned)a2 | ((unsigned)a3 << 16);
        const unsigned bh01 = (unsigned)b0 | ((unsigned)b1 << 16);
        const unsigned bh23 = (unsigned)b2 | ((unsigned)b3 << 16);
        const unsigned al01 = (unsigned)f2bf(pA[0]-bf2f(a0)) | ((unsigned)f2bf(pA[1]-bf2f(a1)) << 16);
        const unsigned al23 = (unsigned)f2bf(pA[2]-bf2f(a2)) | ((unsigned)f2bf(pA[3]-bf2f(a3)) << 16);
        const unsigned bl01 = (unsigned)f2bf(pB[0]-bf2f(b0)) | ((unsigned)f2bf(pB[1]-bf2f(b1)) << 16);
        const unsigned bl23 = (unsigned)f2bf(pB[2]-bf2f(b2)) | ((unsigned)f2bf(pB[3]-bf2f(b3)) << 16);

        const unsigned hA01 = (unsigned)__shfl((int)ah01, sAl), hB01 = (unsigned)__shfl((int)bh01, sAl);
        const unsigned hA23 = (unsigned)__shfl((int)ah23, sAl), hB23 = (unsigned)__shfl((int)bh23, sAl);
        const unsigned hA45 = (unsigned)__shfl((int)ah01, sBl), hB45 = (unsigned)__shfl((int)bh01, sBl);
        const unsigned hA67 = (unsigned)__shfl((int)ah23, sBl), hB67 = (unsigned)__shfl((int)bh23, sBl);
        const unsigned lA01 = (unsigned)__shfl((int)al01, sAl), lB01 = (unsigned)__shfl((int)bl01, sAl);
        const unsigned lA23 = (unsigned)__shfl((int)al23, sAl), lB23 = (unsigned)__shfl((int)bl23, sAl);
        const unsigned lA45 = (unsigned)__shfl((int)al01, sBl), lB45 = (unsigned)__shfl((int)bl01, sBl);
        const unsigned lA67 = (unsigned)__shfl((int)al23, sBl), lB67 = (unsigned)__shfl((int)bl23, sBl);

        const u32x4 th = { hiT ? hB01 : hA01, hiT ? hB23 : hA23,
                           hiT ? hB45 : hA45, hiT ? hB67 : hA67 };
        const u32x4 tl = { hiT ? lB01 : lA01, hiT ? lB23 : lA23,
                           hiT ? lB45 : lA45, hiT ? lB67 : lA67 };
        const bf16x8 pah = __builtin_bit_cast(bf16x8, th);
        const bf16x8 pal = __builtin_bit_cast(bf16x8, tl);

        #pragma unroll
        for (int ff = 0; ff < 6; ++ff) {
            const long zb = (zrow + ff*16 + lr)*2048 + ((w*256 + c*32 + lg*8) >> 3)*16;
            const bf16x8 zh8 = *(const bf16x8*)(Zi + zb);
            const bf16x8 zl8 = *(const bf16x8*)(Zi + zb + 8);
            acc2[ff] = __builtin_amdgcn_mfma_f32_16x16x32_bf16(pah, zh8, acc2[ff], 0, 0, 0);
            acc2[ff] = __builtin_amdgcn_mfma_f32_16x16x32_bf16(pah, zl8, acc2[ff], 0, 0, 0);
            acc2[ff] = __builtin_amdgcn_mfma_f32_16x16x32_bf16(pal, zh8, acc2[ff], 0, 0, 0);
        }
    }

    // ---- staged deterministic cross-wave reduce (m = lg*4+r, f = ff*16+lr)
    for (int wv = 0; wv < 4; ++wv) {
        if (w == wv) {
            #pragma unroll
            for (int ff = 0; ff < 6; ++ff)
                #pragma unroll
                for (int r = 0; r < 4; ++r) {
                    const int m = lg*4 + r, f = ff*16 + lr;
                    if (wv == 0) outl[m*100 + f] = acc2[ff][r];
                    else         outl[m*100 + f] += acc2[ff][r];
                }
        }
        __syncthreads();
    }
    // ---- phase 4: normalized, coalesced write
    for (int idx = tid; idx < 384; idx += 256) {
        const int f = idx >> 2, mg = idx & 3;
        float4 o;
        o.x = outl[(mg*4+0)*100 + f] * inv16[mg*4+0];
        o.y = outl[(mg*4+1)*100 + f] * inv16[mg*4+1];
        o.z = outl[(mg*4+2)*100 + f] * inv16[mg*4+2];
        o.w = outl[(mg*4+3)*100 + f] * inv16[mg*4+3];
        *(float4*)&Ao[(long)(b*768 + h*96 + f)*1024 + m0 + mg*4] = o;
    }
}

// ---------------------------------------------------------------- VN LayerNorm (+residual) [r1 verbatim]
__global__ __launch_bounds__(256) void k_vnln(
    const float* __restrict__ X, const float* __restrict__ Res,
    const float* __restrict__ g, const float* __restrict__ be,
    float* __restrict__ Out)
{
    const int b  = blockIdx.x >> 5;
    const int n  = ((blockIdx.x & 31) << 5) + threadIdx.x;
    const int ty = threadIdx.y;
    const long bbase = (long)b * (256*3*1024);
    float sum = 0.0f, sq = 0.0f;
    for (int ci = 0; ci < 32; ++ci) {
        const int c = (ty << 5) + ci;
        const long base = bbase + (long)c*3072 + n;
        const float x0 = X[base], x1 = X[base+1024], x2 = X[base+2048];
        const float nr = sqrtf(x0*x0 + x1*x1 + x2*x2) + VN_EPS;
        sum += nr; sq += nr*nr;
    }
    __shared__ float s_sum[8][32], s_sq[8][32];
    s_sum[ty][threadIdx.x] = sum; s_sq[ty][threadIdx.x] = sq;
    __syncthreads();
    __shared__ float s_mu[32], s_rs[32];
    if (ty == 0) {
        float S = 0.0f, Q = 0.0f;
        #pragma unroll
        for (int w = 0; w < 8; ++w) { S += s_sum[w][threadIdx.x]; Q += s_sq[w][threadIdx.x]; }
        const float mu = S / 256.0f;
        s_mu[threadIdx.x] = mu;
        s_rs[threadIdx.x] = rsqrtf(Q / 256.0f - mu*mu + LN_EPS);
    }
    __syncthreads();
    const float mu = s_mu[threadIdx.x], rstd = s_rs[threadIdx.x];
    for (int ci = 0; ci < 32; ++ci) {
        const int c = (ty << 5) + ci;
        const long base = bbase + (long)c*3072 + n;
        const float x0 = X[base], x1 = X[base+1024], x2 = X[base+2048];
        const float nr = sqrtf(x0*x0 + x1*x1 + x2*x2) + VN_EPS;
        const float ln = (nr - mu) * rstd * g[c] + be[c];
        const float s  = ln / nr;
        float o0 = x0*s, o1 = x1*s, o2 = x2*s;
        if (Res) { o0 += Res[base]; o1 += Res[base+1024]; o2 += Res[base+2048]; }
        Out[base] = o0; Out[base+1024] = o1; Out[base+2048] = o2;
    }
}

// ---------------------------------------------------------------- BN stats [r7 verbatim]
__global__ __launch_bounds__(256) void k_bnstats(
    const float* __restrict__ X, float* __restrict__ bnst)
{
    const int c = blockIdx.x;
    const int t = threadIdx.x;
    float sum = 0.0f, sq = 0.0f;
    for (int b = 0; b < 8; ++b) {
        const long rowbase = ((long)(b*256 + c)) * 3072;
        for (int n0 = 0; n0 < 1024; n0 += 256) {
            const int n = n0 + t;
            const float x0 = X[rowbase + n], x1 = X[rowbase + 1024 + n], x2 = X[rowbase + 2048 + n];
            const float nr = sqrtf(x0*x0 + x1*x1 + x2*x2) + VN_EPS;
            sum += nr; sq += nr*nr;
        }
    }
    #pragma unroll
    for (int off = 32; off > 0; off >>= 1) {
        sum += __shfl_xor(sum, off);
        sq  += __shfl_xor(sq,  off);
    }
    __shared__ float rs[4], rq[4];
    if ((t & 63) == 0) { rs[t >> 6] = sum; rq[t >> 6] = sq; }
    __syncthreads();
    if (t == 0) {
        const float S = rs[0]+rs[1]+rs[2]+rs[3];
        const float Q = rq[0]+rq[1]+rq[2]+rq[3];
        const float mu = S / 8192.0f;
        bnst[c] = mu;
        bnst[256 + c] = rsqrtf(Q / 8192.0f - mu*mu + BN_EPS);
    }
}

// ---------------------------------------------------------------- BN apply in place [r7 verbatim]
__global__ __launch_bounds__(256) void k_bnapply(
    float* __restrict__ X, const float* __restrict__ bnst,
    const float* __restrict__ g, const float* __restrict__ be)
{
    const long i = (long)blockIdx.x * 256 + threadIdx.x;
    const int  n  = (int)(i & 1023);
    const long bc = i >> 10;
    const int  c  = (int)(bc & 255);
    const long base = bc * 3072 + n;
    const float x0 = X[base], x1 = X[base+1024], x2 = X[base+2048];
    const float nr = sqrtf(x0*x0 + x1*x1 + x2*x2) + VN_EPS;
    const float bn = (nr - bnst[c]) * bnst[256 + c] * g[c] + be[c];
    const float s  = bn / nr;
    X[base]      = x0*s;
    X[base+1024] = x1*s;
    X[base+2048] = x2*s;
}

// ---------------------------------------------------------------- VN leaky relu (slope 0) in place [r7 verbatim]
__global__ __launch_bounds__(256) void k_leaky(
    float* __restrict__ X, const float* __restrict__ Dd)
{
    const long i = (long)blockIdx.x * 256 + threadIdx.x;
    const long base = (i >> 10) * 3072 + (i & 1023);
    const float x0 = X[base], x1 = X[base+1024], x2 = X[base+2048];
    const float d0 = Dd[base], d1 = Dd[base+1024], d2 = Dd[base+2048];
    const float dot = x0*d0 + x1*d1 + x2*d2;
    if (dot < 0.0f) {
        const float f = dot / (d0*d0 + d1*d1 + d2*d2 + VN_EPS);
        X[base]      = x0 - f*d0;
        X[base+1024] = x1 - f*d1;
        X[base+2048] = x2 - f*d2;
    }
}

// ================================================================ launch
extern "C" void kernel_launch(void* const* d_in, const int* in_sizes, int n_in,
                              void* d_out, int out_size, void* d_ws, size_t ws_size,
                              hipStream_t stream)
{
    const float* x    = (const float*)d_in[0];
    const float* Wq   = (const float*)d_in[1];
    const float* bq   = (const float*)d_in[2];
    const float* Wk   = (const float*)d_in[3];
    const float* bk   = (const float*)d_in[4];
    const float* Wz   = (const float*)d_in[5];
    const float* bz   = (const float*)d_in[6];
    const float* Wo   = (const float*)d_in[7];
    const float* bo   = (const float*)d_in[8];
    const float* ln1g = (const float*)d_in[9];
    const float* ln1b = (const float*)d_in[10];
    const float* Wm1  = (const float*)d_in[11];
    const float* bm1  = (const float*)d_in[12];
    const float* bng  = (const float*)d_in[13];
    const float* bnb  = (const float*)d_in[14];
    const float* Wr   = (const float*)d_in[15];
    const float* Wm2  = (const float*)d_in[16];
    const float* bm2  = (const float*)d_in[17];
    const float* ln2g = (const float*)d_in[18];
    const float* ln2b = (const float*)d_in[19];
    float* out = (float*)d_out;

    char* wsb = (char*)d_ws;
    u16*   qi  = (u16*)(wsb + 0);              // [64][1024][192] u16 = 25165824 B
    u16*   ki  = (u16*)(wsb + 25165824);       // same
    u16*   zi  = (u16*)(wsb + 50331648);       // [6144][2048] u16 = 25165824 B
    u16*   wth = (u16*)(wsb + 109051904);
    u16*   wtl = (u16*)(wsb + 109969408);
    float* uall= (float*)(wsb + 110886912);
    float* bnst= (float*)(wsb + 110905344);
    // phase C aliases (attention buffers dead)
    float* ao  = out;                          // d_out as attn-out scratch
    float* y0f = (float*)(wsb + 0);
    float* y   = (float*)(wsb + 25165824);
    float* h   = (float*)(wsb + 50331648);
    float* dv  = (float*)(wsb + 75497472);
    float* h2  = (float*)(wsb + 0);

    const dim3 GC(16, 4, 24);

    k_u<<<6, 256, 0, stream>>>(bq, bk, bz, bo, bm1, bm2, uall);
    k_wtrans<<<dim3(4,4,7), 256, 0, stream>>>(Wq, Wk, Wz, Wo, Wm1, Wr, Wm2, wth, wtl);

    // projections
    k_cgemm<2><<<GC, 256, 0, stream>>>(x, wth + 0*65536, wtl + 0*65536, uall + 0*768, nullptr, qi);
    k_cgemm<2><<<GC, 256, 0, stream>>>(x, wth + 1*65536, wtl + 1*65536, uall + 1*768, nullptr, ki);
    k_cgemm<1><<<GC, 256, 0, stream>>>(x, wth + 2*65536, wtl + 2*65536, uall + 2*768, nullptr, zi);

    // fused attention (interleaved hi/lo loads, XCD-swizzled)
    k_attn<<<4096, 256, 0, stream>>>(qi, ki, zi, ao);

    // out projection + LN1 (+ residual x)
    k_cgemm<0><<<GC, 256, 0, stream>>>(ao, wth + 3*65536, wtl + 3*65536, uall + 3*768, y0f, nullptr);
    k_vnln<<<256, dim3(32,8), 0, stream>>>(y0f, x, ln1g, ln1b, y);

    // MLP
    k_cgemm<0><<<GC, 256, 0, stream>>>(y, wth + 4*65536, wtl + 4*65536, uall + 4*768, h, nullptr);
    k_bnstats<<<256, 256, 0, stream>>>(h, bnst);
    k_bnapply<<<8192, 256, 0, stream>>>(h, bnst, bng, bnb);
    k_cgemm<0><<<GC, 256, 0, stream>>>(h, wth + 5*65536, wtl + 5*65536, (const float*)nullptr, dv, nullptr);
    k_leaky<<<8192, 256, 0, stream>>>(h, dv);
    k_cgemm<0><<<GC, 256, 0, stream>>>(h, wth + 6*65536, wtl + 6*65536, uall + 5*768, h2, nullptr);
    k_vnln<<<256, dim3(32,8), 0, stream>>>(h2, y, ln2g, ln2b, out);
}

// Round 17
// 484.707 us; speedup vs baseline: 1.3817x; 1.3817x over previous
//
#include <hip/hip_runtime.h>
#include <math.h>

typedef __attribute__((ext_vector_type(8))) short bf16x8;
typedef __attribute__((ext_vector_type(4))) float f32x4;
typedef unsigned short u16;
typedef __attribute__((ext_vector_type(4))) unsigned short u16x4;
typedef __attribute__((ext_vector_type(8))) unsigned short u16x8;
typedef __attribute__((ext_vector_type(4))) unsigned int u32x4;

#define VN_EPS 1e-6f
#define LN_EPS 1e-5f
#define BN_EPS 1e-5f
#define ISQ 0.10206207261596575f

__device__ __forceinline__ u16 f2bf(float f) {
    unsigned u = __builtin_bit_cast(unsigned, f);
    return (u16)((u + 0x7FFFu + ((u >> 16) & 1u)) >> 16);
}
__device__ __forceinline__ float bf2f(u16 h) {
    unsigned u = ((unsigned)h) << 16;
    return __builtin_bit_cast(float, u);
}

// ---------------------------------------------------------------- u = eps*b/||b||
__global__ __launch_bounds__(256) void k_u(
    const float* __restrict__ b0, const float* __restrict__ b1,
    const float* __restrict__ b2, const float* __restrict__ b3,
    const float* __restrict__ b4, const float* __restrict__ b5,
    float* __restrict__ uall)
{
    const float* bs[6] = {b0, b1, b2, b3, b4, b5};
    const float* bp = bs[blockIdx.x];
    const int co = threadIdx.x;
    const float v0 = bp[co*3+0], v1 = bp[co*3+1], v2 = bp[co*3+2];
    const float inv = rsqrtf(v0*v0 + v1*v1 + v2*v2);
    float* u = uall + blockIdx.x*768 + co*3;
    u[0] = VN_EPS*v0*inv; u[1] = VN_EPS*v1*inv; u[2] = VN_EPS*v2*inv;
}

// ---------------------------------------------------------------- W f32 [i][o] -> Wt hi/lo bf16 [o][i]
__global__ __launch_bounds__(256) void k_wtrans(
    const float* __restrict__ w0, const float* __restrict__ w1,
    const float* __restrict__ w2, const float* __restrict__ w3,
    const float* __restrict__ w4, const float* __restrict__ w5,
    const float* __restrict__ w6, u16* __restrict__ wth, u16* __restrict__ wtl)
{
    const int wi = blockIdx.z;
    const float* W = (wi==0)?w0:(wi==1)?w1:(wi==2)?w2:(wi==3)?w3:(wi==4)?w4:(wi==5)?w5:w6;
    u16* WtH = wth + (long)wi*65536;
    u16* WtL = wtl + (long)wi*65536;
    const int i0 = blockIdx.y*64, o0 = blockIdx.x*64;
    __shared__ float st[64][67];
    const int t = threadIdx.x, q = t >> 6, lane = t & 63;
    for (int j = 0; j < 16; ++j) {
        const int i = q*16 + j;
        st[i][lane] = W[(i0 + i)*256 + o0 + lane];
    }
    __syncthreads();
    for (int j = 0; j < 16; ++j) {
        const int o = q*16 + j;
        const float v = st[lane][o];
        const u16 hi = f2bf(v);
        WtH[(o0 + o)*256 + i0 + lane] = hi;
        WtL[(o0 + o)*256 + i0 + lane] = f2bf(v - bf2f(hi));
    }
}

// ---------------------------------------------------------------- split-bf16 channel GEMM [r15 verbatim]
template<int MODE>
__global__ __launch_bounds__(256) void k_cgemm(
    const float* __restrict__ X, const u16* __restrict__ WtH, const u16* __restrict__ WtL,
    const float* __restrict__ U,
    float* __restrict__ OutF, u16* __restrict__ OutH, u16* __restrict__ OutL)
{
    __shared__ u16 sh[32768];
    const int tid = threadIdx.x;
    const int b = blockIdx.z / 3, d = blockIdx.z % 3;
    const int n0 = blockIdx.x * 64;
    const int co0 = blockIdx.y * 64;

    {
        const int tn = (tid & 15) * 4;
        const int ti = (tid >> 4) * 4;
        #pragma unroll
        for (int it = 0; it < 4; ++it) {
            const int i_l = it*64 + ti;
            const long rb = (((long)(b*256 + i_l))*3 + d)*1024 + n0 + tn;
            const float4 r0 = *(const float4*)&X[rb];
            const float4 r1 = *(const float4*)&X[rb + 3072];
            const float4 r2 = *(const float4*)&X[rb + 6144];
            const float4 r3 = *(const float4*)&X[rb + 9216];
            const float vals[4][4] = {
                {r0.x, r1.x, r2.x, r3.x},
                {r0.y, r1.y, r2.y, r3.y},
                {r0.z, r1.z, r2.z, r3.z},
                {r0.w, r1.w, r2.w, r3.w}};
            #pragma unroll
            for (int j = 0; j < 4; ++j) {
                const int n = tn + j;
                u16x4 hv, lv;
                #pragma unroll
                for (int e = 0; e < 4; ++e) {
                    const float v = vals[j][e];
                    const u16 hi = f2bf(v);
                    hv[e] = hi;
                    lv[e] = f2bf(v - bf2f(hi));
                }
                const int slot = i_l >> 3;
                const int idx = n*256 + ((((slot ^ (n & 7)) << 3)) | (i_l & 4));
                *(u16x4*)&sh[idx] = hv;
                *(u16x4*)&sh[16384 + idx] = lv;
            }
        }
    }
    __syncthreads();

    const int w = tid >> 6, l = tid & 63;
    const int lr = l & 15, lg = l >> 4;

    f32x4 zero = {0.f, 0.f, 0.f, 0.f};
    f32x4 acc[4] = {zero, zero, zero, zero};

    const long arow = (long)(co0 + w*16 + lr)*256 + lg*8;
    #pragma unroll
    for (int s = 0; s < 8; ++s) {
        const bf16x8 ah = *(const bf16x8*)(WtH + arow + s*32);
        const bf16x8 al = *(const bf16x8*)(WtL + arow + s*32);
        #pragma unroll
        for (int ni = 0; ni < 4; ++ni) {
            const int row = ni*16 + lr;
            const int slot = s*4 + lg;
            const int idx = row*256 + ((slot ^ (row & 7)) << 3);
            const bf16x8 bh_ = *(const bf16x8*)&sh[idx];
            const bf16x8 bl_ = *(const bf16x8*)&sh[16384 + idx];
            acc[ni] = __builtin_amdgcn_mfma_f32_16x16x32_bf16(ah, bh_, acc[ni], 0, 0, 0);
            acc[ni] = __builtin_amdgcn_mfma_f32_16x16x32_bf16(ah, bl_, acc[ni], 0, 0, 0);
            acc[ni] = __builtin_amdgcn_mfma_f32_16x16x32_bf16(al, bh_, acc[ni], 0, 0, 0);
        }
    }

    if constexpr (MODE == 0) {
        #pragma unroll
        for (int ni = 0; ni < 4; ++ni)
            #pragma unroll
            for (int r = 0; r < 4; ++r) {
                const int co = co0 + w*16 + lg*4 + r;
                const int nn = n0 + ni*16 + lr;
                float v = acc[ni][r];
                if (U) v += U[co*3 + d];
                OutF[(((long)(b*256 + co))*3 + d)*1024 + nn] = v;
            }
    } else if constexpr (MODE == 1) {
        #pragma unroll
        for (int ni = 0; ni < 4; ++ni)
            #pragma unroll
            for (int r = 0; r < 4; ++r) {
                const int co = co0 + w*16 + lg*4 + r;
                const int nn = n0 + ni*16 + lr;
                float v = acc[ni][r] + U[co*3 + d];
                const long idx = (((long)(b*256 + co))*3 + d)*1024 + nn;
                const u16 hi = f2bf(v);
                OutH[idx] = hi;
                OutL[idx] = f2bf(v - bf2f(hi));
            }
    } else {
        __syncthreads();
        u16* olh = sh;
        u16* oll = sh + 8448;
        #pragma unroll
        for (int ni = 0; ni < 4; ++ni)
            #pragma unroll
            for (int r = 0; r < 4; ++r) {
                const int co_l = w*16 + lg*4 + r;
                float v = acc[ni][r] + U[(co0 + co_l)*3 + d];
                const u16 hi = f2bf(v);
                olh[co_l*66 + ni*16 + lr] = hi;
                oll[co_l*66 + ni*16 + lr] = f2bf(v - bf2f(hi));
            }
        __syncthreads();
        const int n_l = tid & 63, grp = tid >> 6;
        const int h = (co0 >> 5) + (grp >> 1);
        const long base = ((long)(b*8 + h)*1024 + n0 + n_l)*96 + d*32 + (grp & 1)*16;
        u16x8 v0h, v1h, v0l, v1l;
        #pragma unroll
        for (int p = 0; p < 8; ++p) {
            v0h[p] = olh[(grp*16 + p)*66 + n_l];
            v1h[p] = olh[(grp*16 + 8 + p)*66 + n_l];
            v0l[p] = oll[(grp*16 + p)*66 + n_l];
            v1l[p] = oll[(grp*16 + 8 + p)*66 + n_l];
        }
        *(u16x8*)&OutH[base]     = v0h;
        *(u16x8*)&OutH[base + 8] = v1h;
        *(u16x8*)&OutL[base]     = v0l;
        *(u16x8*)&OutL[base + 8] = v1l;
    }
}

// ---------------------------------------------------------------- fused attention: 64 m-rows/block, LDS-staged K/Z, flash over 16x64-n chunks
__global__ __launch_bounds__(256) void k_attn(
    const u16* __restrict__ Qh, const u16* __restrict__ Ql,
    const u16* __restrict__ Kh, const u16* __restrict__ Kl,
    const u16* __restrict__ Zh, const u16* __restrict__ Zl,
    float* __restrict__ Ao)
{
    const int i = blockIdx.x;            // 0..1023
    const int xcd = i & 7;
    const int j = i >> 3;                // 0..127
    const int bh = xcd*8 + (j >> 4);
    const int mt = j & 15;
    const int b = bh >> 3, h = bh & 7;
    const int tid = threadIdx.x;
    const int w = tid >> 6, l = tid & 63, lr = l & 15, lg = l >> 4;
    const int m0 = mt*64 + w*16;         // wave-owned 16 m-rows

    __shared__ u16 khi[64*104], klo[64*104];   // K chunk [nl][ch], pad 104
    __shared__ u16 zhi[96*72],  zlo[96*72];    // Z chunk [f][nl], pad 72

    f32x4 zero = {0.f, 0.f, 0.f, 0.f};

    // Q B-frags (once)
    const long qbase = ((long)bh*1024 + m0 + lr)*96 + lg*8;
    bf16x8 qhf[3], qlf[3];
    #pragma unroll
    for (int s = 0; s < 3; ++s) {
        qhf[s] = *(const bf16x8*)(Qh + qbase + s*32);
        qlf[s] = *(const bf16x8*)(Ql + qbase + s*32);
    }

    f32x4 acc2[6];
    #pragma unroll
    for (int f = 0; f < 6; ++f) acc2[f] = zero;
    float run_m = -1e30f, run_l = 0.f;

    const long zrow = (long)(b*768 + h*96);
    const int sAl = lr + ((lg & 1) << 5);
    const int sBl = sAl + 16;
    const bool hiT = (lg & 2) != 0;

    for (int c = 0; c < 16; ++c) {
        const int n0 = c*64;
        __syncthreads();   // previous chunk's reads complete
        // ---- cooperative stage: K rows n0..n0+63 (contiguous 6144 u16), Z 96 rows x 64 cols
        {
            const long kgb = ((long)bh*1024 + n0)*96;
            #pragma unroll
            for (int it = 0; it < 3; ++it) {
                const int id = it*256 + tid;          // 0..767
                const int row = id / 12, off = (id % 12)*8;
                *(u16x8*)&khi[row*104 + off] = *(const u16x8*)(Kh + kgb + id*8);
                *(u16x8*)&klo[row*104 + off] = *(const u16x8*)(Kl + kgb + id*8);
            }
            #pragma unroll
            for (int it = 0; it < 3; ++it) {
                const int id = it*256 + tid;          // 0..767
                const int f = id >> 3, off = (id & 7)*8;
                const long zg = (zrow + f)*1024 + n0 + off;
                *(u16x8*)&zhi[f*72 + off] = *(const u16x8*)(Zh + zg);
                *(u16x8*)&zlo[f*72 + off] = *(const u16x8*)(Zl + zg);
            }
        }
        __syncthreads();

        // ---- QK^T: 4 swapped tiles from LDS (lane: m=lr, n = n0 + t*16 + lg*4 + r)
        f32x4 sc[4];
        #pragma unroll
        for (int t = 0; t < 4; ++t) {
            const int krow = (t*16 + lr)*104 + lg*8;
            f32x4 a = zero;
            #pragma unroll
            for (int s = 0; s < 3; ++s) {
                const bf16x8 khf = *(const bf16x8*)&khi[krow + s*32];
                const bf16x8 klf = *(const bf16x8*)&klo[krow + s*32];
                a = __builtin_amdgcn_mfma_f32_16x16x32_bf16(khf, qhf[s], a, 0, 0, 0);
                a = __builtin_amdgcn_mfma_f32_16x16x32_bf16(khf, qlf[s], a, 0, 0, 0);
                a = __builtin_amdgcn_mfma_f32_16x16x32_bf16(klf, qhf[s], a, 0, 0, 0);
            }
            sc[t] = a;
        }

        // ---- online softmax update (row m = lr; reduce across lg)
        float tmax = -1e30f;
        #pragma unroll
        for (int t = 0; t < 4; ++t)
            #pragma unroll
            for (int r = 0; r < 4; ++r)
                tmax = fmaxf(tmax, sc[t][r]);
        tmax = fmaxf(tmax, __shfl_xor(tmax, 16));
        tmax = fmaxf(tmax, __shfl_xor(tmax, 32));
        const float m_new = fmaxf(run_m, tmax);
        const float fr = __expf((run_m - m_new)*ISQ);
        float sm = 0.f;
        #pragma unroll
        for (int t = 0; t < 4; ++t)
            #pragma unroll
            for (int r = 0; r < 4; ++r) {
                const float p = __expf((sc[t][r] - m_new)*ISQ);
                sc[t][r] = p;
                sm += p;
            }
        sm += __shfl_xor(sm, 16);
        sm += __shfl_xor(sm, 32);
        run_l = run_l * fr + sm;
        run_m = m_new;
        #pragma unroll
        for (int r = 0; r < 4; ++r) {
            const float fm = __shfl(fr, lg*4 + r);
            #pragma unroll
            for (int ff = 0; ff < 6; ++ff) acc2[ff][r] *= fm;
        }

        // ---- PV: 2 kb of 32 n; P via shfl exchange into K=32 A-frags [r15-verified]
        #pragma unroll
        for (int kb = 0; kb < 2; ++kb) {
            const f32x4 pA = sc[2*kb], pB = sc[2*kb + 1];
            const u16 a0 = f2bf(pA[0]), a1 = f2bf(pA[1]), a2 = f2bf(pA[2]), a3 = f2bf(pA[3]);
            const u16 b0 = f2bf(pB[0]), b1 = f2bf(pB[1]), b2 = f2bf(pB[2]), b3 = f2bf(pB[3]);
            const unsigned ah01 = (unsigned)a0 | ((unsigned)a1 << 16);
            const unsigned ah23 = (unsigned)a2 | ((unsigned)a3 << 16);
            const unsigned bh01 = (unsigned)b0 | ((unsigned)b1 << 16);
            const unsigned bh23 = (unsigned)b2 | ((unsigned)b3 << 16);
            const unsigned al01 = (unsigned)f2bf(pA[0]-bf2f(a0)) | ((unsigned)f2bf(pA[1]-bf2f(a1)) << 16);
            const unsigned al23 = (unsigned)f2bf(pA[2]-bf2f(a2)) | ((unsigned)f2bf(pA[3]-bf2f(a3)) << 16);
            const unsigned bl01 = (unsigned)f2bf(pB[0]-bf2f(b0)) | ((unsigned)f2bf(pB[1]-bf2f(b1)) << 16);
            const unsigned bl23 = (unsigned)f2bf(pB[2]-bf2f(b2)) | ((unsigned)f2bf(pB[3]-bf2f(b3)) << 16);

            const unsigned hA01 = (unsigned)__shfl((int)ah01, sAl), hB01 = (unsigned)__shfl((int)bh01, sAl);
            const unsigned hA23 = (unsigned)__shfl((int)ah23, sAl), hB23 = (unsigned)__shfl((int)bh23, sAl);
            const unsigned hA45 = (unsigned)__shfl((int)ah01, sBl), hB45 = (unsigned)__shfl((int)bh01, sBl);
            const unsigned hA67 = (unsigned)__shfl((int)ah23, sBl), hB67 = (unsigned)__shfl((int)bh23, sBl);
            const unsigned lA01 = (unsigned)__shfl((int)al01, sAl), lB01 = (unsigned)__shfl((int)bl01, sAl);
            const unsigned lA23 = (unsigned)__shfl((int)al23, sAl), lB23 = (unsigned)__shfl((int)bl23, sAl);
            const unsigned lA45 = (unsigned)__shfl((int)al01, sBl), lB45 = (unsigned)__shfl((int)bl01, sBl);
            const unsigned lA67 = (unsigned)__shfl((int)al23, sBl), lB67 = (unsigned)__shfl((int)bl23, sBl);

            const u32x4 th = { hiT ? hB01 : hA01, hiT ? hB23 : hA23,
                               hiT ? hB45 : hA45, hiT ? hB67 : hA67 };
            const u32x4 tl = { hiT ? lB01 : lA01, hiT ? lB23 : lA23,
                               hiT ? lB45 : lA45, hiT ? lB67 : lA67 };
            const bf16x8 pah = __builtin_bit_cast(bf16x8, th);
            const bf16x8 pal = __builtin_bit_cast(bf16x8, tl);

            #pragma unroll
            for (int ff = 0; ff < 6; ++ff) {
                const int zoff = (ff*16 + lr)*72 + kb*32 + lg*8;
                const bf16x8 zh8 = *(const bf16x8*)&zhi[zoff];
                const bf16x8 zl8 = *(const bf16x8*)&zlo[zoff];
                acc2[ff] = __builtin_amdgcn_mfma_f32_16x16x32_bf16(pah, zh8, acc2[ff], 0, 0, 0);
                acc2[ff] = __builtin_amdgcn_mfma_f32_16x16x32_bf16(pah, zl8, acc2[ff], 0, 0, 0);
                acc2[ff] = __builtin_amdgcn_mfma_f32_16x16x32_bf16(pal, zh8, acc2[ff], 0, 0, 0);
            }
        }
    }

    // ---- normalize and write (D: row m = lg*4+r, col f = ff*16+lr -> Ao[f][m])
    const float lrec = 1.0f / run_l;
    #pragma unroll
    for (int r = 0; r < 4; ++r) {
        const float iv = __shfl(lrec, lg*4 + r);
        #pragma unroll
        for (int ff = 0; ff < 6; ++ff) acc2[ff][r] *= iv;
    }
    #pragma unroll
    for (int ff = 0; ff < 6; ++ff) {
        // acc2[ff][r] = O[m = lg*4+r][f = ff*16+lr]; write transposed per element
        #pragma unroll
        for (int r = 0; r < 4; ++r)
            Ao[(zrow + ff*16 + lr)*1024 + m0 + lg*4 + r] = acc2[ff][r];
    }
}

// ---------------------------------------------------------------- VN LayerNorm (+residual) [r1 verbatim]
__global__ __launch_bounds__(256) void k_vnln(
    const float* __restrict__ X, const float* __restrict__ Res,
    const float* __restrict__ g, const float* __restrict__ be,
    float* __restrict__ Out)
{
    const int b  = blockIdx.x >> 5;
    const int n  = ((blockIdx.x & 31) << 5) + threadIdx.x;
    const int ty = threadIdx.y;
    const long bbase = (long)b * (256*3*1024);
    float sum = 0.0f, sq = 0.0f;
    for (int ci = 0; ci < 32; ++ci) {
        const int c = (ty << 5) + ci;
        const long base = bbase + (long)c*3072 + n;
        const float x0 = X[base], x1 = X[base+1024], x2 = X[base+2048];
        const float nr = sqrtf(x0*x0 + x1*x1 + x2*x2) + VN_EPS;
        sum += nr; sq += nr*nr;
    }
    __shared__ float s_sum[8][32], s_sq[8][32];
    s_sum[ty][threadIdx.x] = sum; s_sq[ty][threadIdx.x] = sq;
    __syncthreads();
    __shared__ float s_mu[32], s_rs[32];
    if (ty == 0) {
        float S = 0.0f, Q = 0.0f;
        #pragma unroll
        for (int w = 0; w < 8; ++w) { S += s_sum[w][threadIdx.x]; Q += s_sq[w][threadIdx.x]; }
        const float mu = S / 256.0f;
        s_mu[threadIdx.x] = mu;
        s_rs[threadIdx.x] = rsqrtf(Q / 256.0f - mu*mu + LN_EPS);
    }
    __syncthreads();
    const float mu = s_mu[threadIdx.x], rstd = s_rs[threadIdx.x];
    for (int ci = 0; ci < 32; ++ci) {
        const int c = (ty << 5) + ci;
        const long base = bbase + (long)c*3072 + n;
        const float x0 = X[base], x1 = X[base+1024], x2 = X[base+2048];
        const float nr = sqrtf(x0*x0 + x1*x1 + x2*x2) + VN_EPS;
        const float ln = (nr - mu) * rstd * g[c] + be[c];
        const float s  = ln / nr;
        float o0 = x0*s, o1 = x1*s, o2 = x2*s;
        if (Res) { o0 += Res[base]; o1 += Res[base+1024]; o2 += Res[base+2048]; }
        Out[base] = o0; Out[base+1024] = o1; Out[base+2048] = o2;
    }
}

// ---------------------------------------------------------------- BN stats [r7 verbatim]
__global__ __launch_bounds__(256) void k_bnstats(
    const float* __restrict__ X, float* __restrict__ bnst)
{
    const int c = blockIdx.x;
    const int t = threadIdx.x;
    float sum = 0.0f, sq = 0.0f;
    for (int b = 0; b < 8; ++b) {
        const long rowbase = ((long)(b*256 + c)) * 3072;
        for (int n0 = 0; n0 < 1024; n0 += 256) {
            const int n = n0 + t;
            const float x0 = X[rowbase + n], x1 = X[rowbase + 1024 + n], x2 = X[rowbase + 2048 + n];
            const float nr = sqrtf(x0*x0 + x1*x1 + x2*x2) + VN_EPS;
            sum += nr; sq += nr*nr;
        }
    }
    #pragma unroll
    for (int off = 32; off > 0; off >>= 1) {
        sum += __shfl_xor(sum, off);
        sq  += __shfl_xor(sq,  off);
    }
    __shared__ float rs[4], rq[4];
    if ((t & 63) == 0) { rs[t >> 6] = sum; rq[t >> 6] = sq; }
    __syncthreads();
    if (t == 0) {
        const float S = rs[0]+rs[1]+rs[2]+rs[3];
        const float Q = rq[0]+rq[1]+rq[2]+rq[3];
        const float mu = S / 8192.0f;
        bnst[c] = mu;
        bnst[256 + c] = rsqrtf(Q / 8192.0f - mu*mu + BN_EPS);
    }
}

// ---------------------------------------------------------------- BN apply in place [r7 verbatim]
__global__ __launch_bounds__(256) void k_bnapply(
    float* __restrict__ X, const float* __restrict__ bnst,
    const float* __restrict__ g, const float* __restrict__ be)
{
    const long i = (long)blockIdx.x * 256 + threadIdx.x;
    const int  n  = (int)(i & 1023);
    const long bc = i >> 10;
    const int  c  = (int)(bc & 255);
    const long base = bc * 3072 + n;
    const float x0 = X[base], x1 = X[base+1024], x2 = X[base+2048];
    const float nr = sqrtf(x0*x0 + x1*x1 + x2*x2) + VN_EPS;
    const float bn = (nr - bnst[c]) * bnst[256 + c] * g[c] + be[c];
    const float s  = bn / nr;
    X[base]      = x0*s;
    X[base+1024] = x1*s;
    X[base+2048] = x2*s;
}

// ---------------------------------------------------------------- VN leaky relu (slope 0) in place [r7 verbatim]
__global__ __launch_bounds__(256) void k_leaky(
    float* __restrict__ X, const float* __restrict__ Dd)
{
    const long i = (long)blockIdx.x * 256 + threadIdx.x;
    const long base = (i >> 10) * 3072 + (i & 1023);
    const float x0 = X[base], x1 = X[base+1024], x2 = X[base+2048];
    const float d0 = Dd[base], d1 = Dd[base+1024], d2 = Dd[base+2048];
    const float dot = x0*d0 + x1*d1 + x2*d2;
    if (dot < 0.0f) {
        const float f = dot / (d0*d0 + d1*d1 + d2*d2 + VN_EPS);
        X[base]      = x0 - f*d0;
        X[base+1024] = x1 - f*d1;
        X[base+2048] = x2 - f*d2;
    }
}

// ================================================================ launch
extern "C" void kernel_launch(void* const* d_in, const int* in_sizes, int n_in,
                              void* d_out, int out_size, void* d_ws, size_t ws_size,
                              hipStream_t stream)
{
    const float* x    = (const float*)d_in[0];
    const float* Wq   = (const float*)d_in[1];
    const float* bq   = (const float*)d_in[2];
    const float* Wk   = (const float*)d_in[3];
    const float* bk   = (const float*)d_in[4];
    const float* Wz   = (const float*)d_in[5];
    const float* bz   = (const float*)d_in[6];
    const float* Wo   = (const float*)d_in[7];
    const float* bo   = (const float*)d_in[8];
    const float* ln1g = (const float*)d_in[9];
    const float* ln1b = (const float*)d_in[10];
    const float* Wm1  = (const float*)d_in[11];
    const float* bm1  = (const float*)d_in[12];
    const float* bng  = (const float*)d_in[13];
    const float* bnb  = (const float*)d_in[14];
    const float* Wr   = (const float*)d_in[15];
    const float* Wm2  = (const float*)d_in[16];
    const float* bm2  = (const float*)d_in[17];
    const float* ln2g = (const float*)d_in[18];
    const float* ln2b = (const float*)d_in[19];
    float* out = (float*)d_out;

    char* wsb = (char*)d_ws;
    u16*   qh  = (u16*)(wsb + 0);
    u16*   ql  = (u16*)(wsb + 12582912);
    u16*   kh  = (u16*)(wsb + 25165824);
    u16*   kl  = (u16*)(wsb + 37748736);
    u16*   zh  = (u16*)(wsb + 50331648);
    u16*   zl  = (u16*)(wsb + 62914560);
    u16*   wth = (u16*)(wsb + 109051904);
    u16*   wtl = (u16*)(wsb + 109969408);
    float* uall= (float*)(wsb + 110886912);
    float* bnst= (float*)(wsb + 110905344);
    // phase C aliases (attention buffers dead)
    float* ao  = out;                          // d_out as attn-out scratch
    float* y0f = (float*)(wsb + 0);
    float* y   = (float*)(wsb + 25165824);
    float* h   = (float*)(wsb + 50331648);
    float* dv  = (float*)(wsb + 75497472);
    float* h2  = (float*)(wsb + 0);

    const dim3 GC(16, 4, 24);

    k_u<<<6, 256, 0, stream>>>(bq, bk, bz, bo, bm1, bm2, uall);
    k_wtrans<<<dim3(4,4,7), 256, 0, stream>>>(Wq, Wk, Wz, Wo, Wm1, Wr, Wm2, wth, wtl);

    // projections
    k_cgemm<2><<<GC, 256, 0, stream>>>(x, wth + 0*65536, wtl + 0*65536, uall + 0*768, nullptr, qh, ql);
    k_cgemm<2><<<GC, 256, 0, stream>>>(x, wth + 1*65536, wtl + 1*65536, uall + 1*768, nullptr, kh, kl);
    k_cgemm<1><<<GC, 256, 0, stream>>>(x, wth + 2*65536, wtl + 2*65536, uall + 2*768, nullptr, zh, zl);

    // fused attention (LDS-staged K/Z, 64 m-rows/block, XCD-swizzled)
    k_attn<<<1024, 256, 0, stream>>>(qh, ql, kh, kl, zh, zl, ao);

    // out projection + LN1 (+ residual x)
    k_cgemm<0><<<GC, 256, 0, stream>>>(ao, wth + 3*65536, wtl + 3*65536, uall + 3*768, y0f, nullptr, nullptr);
    k_vnln<<<256, dim3(32,8), 0, stream>>>(y0f, x, ln1g, ln1b, y);

    // MLP
    k_cgemm<0><<<GC, 256, 0, stream>>>(y, wth + 4*65536, wtl + 4*65536, uall + 4*768, h, nullptr, nullptr);
    k_bnstats<<<256, 256, 0, stream>>>(h, bnst);
    k_bnapply<<<8192, 256, 0, stream>>>(h, bnst, bng, bnb);
    k_cgemm<0><<<GC, 256, 0, stream>>>(h, wth + 5*65536, wtl + 5*65536, (const float*)nullptr, dv, nullptr, nullptr);
    k_leaky<<<8192, 256, 0, stream>>>(h, dv);
    k_cgemm<0><<<GC, 256, 0, stream>>>(h, wth + 6*65536, wtl + 6*65536, uall + 5*768, h2, nullptr, nullptr);
    k_vnln<<<256, dim3(32,8), 0, stream>>>(h2, y, ln2g, ln2b, out);
}

// Round 18
// 474.726 us; speedup vs baseline: 1.4107x; 1.0210x over previous
//
#include <hip/hip_runtime.h>
#include <math.h>

typedef __attribute__((ext_vector_type(8))) short bf16x8;
typedef __attribute__((ext_vector_type(4))) float f32x4;
typedef unsigned short u16;
typedef __attribute__((ext_vector_type(4))) unsigned short u16x4;
typedef __attribute__((ext_vector_type(8))) unsigned short u16x8;
typedef __attribute__((ext_vector_type(4))) unsigned int u32x4;

#define VN_EPS 1e-6f
#define LN_EPS 1e-5f
#define BN_EPS 1e-5f
#define ISQ 0.10206207261596575f

__device__ __forceinline__ u16 f2bf(float f) {
    unsigned u = __builtin_bit_cast(unsigned, f);
    return (u16)((u + 0x7FFFu + ((u >> 16) & 1u)) >> 16);
}
__device__ __forceinline__ float bf2f(u16 h) {
    unsigned u = ((unsigned)h) << 16;
    return __builtin_bit_cast(float, u);
}

// ---------------------------------------------------------------- u = eps*b/||b||
__global__ __launch_bounds__(256) void k_u(
    const float* __restrict__ b0, const float* __restrict__ b1,
    const float* __restrict__ b2, const float* __restrict__ b3,
    const float* __restrict__ b4, const float* __restrict__ b5,
    float* __restrict__ uall)
{
    const float* bs[6] = {b0, b1, b2, b3, b4, b5};
    const float* bp = bs[blockIdx.x];
    const int co = threadIdx.x;
    const float v0 = bp[co*3+0], v1 = bp[co*3+1], v2 = bp[co*3+2];
    const float inv = rsqrtf(v0*v0 + v1*v1 + v2*v2);
    float* u = uall + blockIdx.x*768 + co*3;
    u[0] = VN_EPS*v0*inv; u[1] = VN_EPS*v1*inv; u[2] = VN_EPS*v2*inv;
}

// ---------------------------------------------------------------- W f32 [i][o] -> Wt hi/lo bf16 [o][i]
__global__ __launch_bounds__(256) void k_wtrans(
    const float* __restrict__ w0, const float* __restrict__ w1,
    const float* __restrict__ w2, const float* __restrict__ w3,
    const float* __restrict__ w4, const float* __restrict__ w5,
    const float* __restrict__ w6, u16* __restrict__ wth, u16* __restrict__ wtl)
{
    const int wi = blockIdx.z;
    const float* W = (wi==0)?w0:(wi==1)?w1:(wi==2)?w2:(wi==3)?w3:(wi==4)?w4:(wi==5)?w5:w6;
    u16* WtH = wth + (long)wi*65536;
    u16* WtL = wtl + (long)wi*65536;
    const int i0 = blockIdx.y*64, o0 = blockIdx.x*64;
    __shared__ float st[64][67];
    const int t = threadIdx.x, q = t >> 6, lane = t & 63;
    for (int j = 0; j < 16; ++j) {
        const int i = q*16 + j;
        st[i][lane] = W[(i0 + i)*256 + o0 + lane];
    }
    __syncthreads();
    for (int j = 0; j < 16; ++j) {
        const int o = q*16 + j;
        const float v = st[lane][o];
        const u16 hi = f2bf(v);
        WtH[(o0 + o)*256 + i0 + lane] = hi;
        WtL[(o0 + o)*256 + i0 + lane] = f2bf(v - bf2f(hi));
    }
}

// ---------------------------------------------------------------- split-bf16 channel GEMM (+ scale)
template<int MODE>
__global__ __launch_bounds__(256) void k_cgemm(
    const float* __restrict__ X, const u16* __restrict__ WtH, const u16* __restrict__ WtL,
    const float* __restrict__ U,
    float* __restrict__ OutF, u16* __restrict__ OutH, u16* __restrict__ OutL, float scale)
{
    __shared__ u16 sh[32768];
    const int tid = threadIdx.x;
    const int b = blockIdx.z / 3, d = blockIdx.z % 3;
    const int n0 = blockIdx.x * 64;
    const int co0 = blockIdx.y * 64;

    {
        const int tn = (tid & 15) * 4;
        const int ti = (tid >> 4) * 4;
        #pragma unroll
        for (int it = 0; it < 4; ++it) {
            const int i_l = it*64 + ti;
            const long rb = (((long)(b*256 + i_l))*3 + d)*1024 + n0 + tn;
            const float4 r0 = *(const float4*)&X[rb];
            const float4 r1 = *(const float4*)&X[rb + 3072];
            const float4 r2 = *(const float4*)&X[rb + 6144];
            const float4 r3 = *(const float4*)&X[rb + 9216];
            const float vals[4][4] = {
                {r0.x, r1.x, r2.x, r3.x},
                {r0.y, r1.y, r2.y, r3.y},
                {r0.z, r1.z, r2.z, r3.z},
                {r0.w, r1.w, r2.w, r3.w}};
            #pragma unroll
            for (int j = 0; j < 4; ++j) {
                const int n = tn + j;
                u16x4 hv, lv;
                #pragma unroll
                for (int e = 0; e < 4; ++e) {
                    const float v = vals[j][e];
                    const u16 hi = f2bf(v);
                    hv[e] = hi;
                    lv[e] = f2bf(v - bf2f(hi));
                }
                const int slot = i_l >> 3;
                const int idx = n*256 + ((((slot ^ (n & 7)) << 3)) | (i_l & 4));
                *(u16x4*)&sh[idx] = hv;
                *(u16x4*)&sh[16384 + idx] = lv;
            }
        }
    }
    __syncthreads();

    const int w = tid >> 6, l = tid & 63;
    const int lr = l & 15, lg = l >> 4;

    f32x4 zero = {0.f, 0.f, 0.f, 0.f};
    f32x4 acc[4] = {zero, zero, zero, zero};

    const long arow = (long)(co0 + w*16 + lr)*256 + lg*8;
    #pragma unroll
    for (int s = 0; s < 8; ++s) {
        const bf16x8 ah = *(const bf16x8*)(WtH + arow + s*32);
        const bf16x8 al = *(const bf16x8*)(WtL + arow + s*32);
        #pragma unroll
        for (int ni = 0; ni < 4; ++ni) {
            const int row = ni*16 + lr;
            const int slot = s*4 + lg;
            const int idx = row*256 + ((slot ^ (row & 7)) << 3);
            const bf16x8 bh_ = *(const bf16x8*)&sh[idx];
            const bf16x8 bl_ = *(const bf16x8*)&sh[16384 + idx];
            acc[ni] = __builtin_amdgcn_mfma_f32_16x16x32_bf16(ah, bh_, acc[ni], 0, 0, 0);
            acc[ni] = __builtin_amdgcn_mfma_f32_16x16x32_bf16(ah, bl_, acc[ni], 0, 0, 0);
            acc[ni] = __builtin_amdgcn_mfma_f32_16x16x32_bf16(al, bh_, acc[ni], 0, 0, 0);
        }
    }

    if constexpr (MODE == 0) {
        #pragma unroll
        for (int ni = 0; ni < 4; ++ni)
            #pragma unroll
            for (int r = 0; r < 4; ++r) {
                const int co = co0 + w*16 + lg*4 + r;
                const int nn = n0 + ni*16 + lr;
                float v = acc[ni][r];
                if (U) v += U[co*3 + d];
                OutF[(((long)(b*256 + co))*3 + d)*1024 + nn] = v;
            }
    } else if constexpr (MODE == 1) {
        #pragma unroll
        for (int ni = 0; ni < 4; ++ni)
            #pragma unroll
            for (int r = 0; r < 4; ++r) {
                const int co = co0 + w*16 + lg*4 + r;
                const int nn = n0 + ni*16 + lr;
                float v = acc[ni][r] + U[co*3 + d];
                const long idx = (((long)(b*256 + co))*3 + d)*1024 + nn;
                const u16 hi = f2bf(v);
                OutH[idx] = hi;
                OutL[idx] = f2bf(v - bf2f(hi));
            }
    } else {
        __syncthreads();
        u16* olh = sh;
        u16* oll = sh + 8448;
        #pragma unroll
        for (int ni = 0; ni < 4; ++ni)
            #pragma unroll
            for (int r = 0; r < 4; ++r) {
                const int co_l = w*16 + lg*4 + r;
                float v = (acc[ni][r] + U[(co0 + co_l)*3 + d]) * scale;
                const u16 hi = f2bf(v);
                olh[co_l*66 + ni*16 + lr] = hi;
                oll[co_l*66 + ni*16 + lr] = f2bf(v - bf2f(hi));
            }
        __syncthreads();
        const int n_l = tid & 63, grp = tid >> 6;
        const int h = (co0 >> 5) + (grp >> 1);
        const long base = ((long)(b*8 + h)*1024 + n0 + n_l)*96 + d*32 + (grp & 1)*16;
        u16x8 v0h, v1h, v0l, v1l;
        #pragma unroll
        for (int p = 0; p < 8; ++p) {
            v0h[p] = olh[(grp*16 + p)*66 + n_l];
            v1h[p] = olh[(grp*16 + 8 + p)*66 + n_l];
            v0l[p] = oll[(grp*16 + p)*66 + n_l];
            v1l[p] = oll[(grp*16 + 8 + p)*66 + n_l];
        }
        *(u16x8*)&OutH[base]     = v0h;
        *(u16x8*)&OutH[base + 8] = v1h;
        *(u16x8*)&OutL[base]     = v0l;
        *(u16x8*)&OutL[base + 8] = v1l;
    }
}

// ---------------------------------------------------------------- fused attention: 64 m-rows/block, TIME-SHARED K/Z LDS buffer
// q pre-scaled by ISQ at projection. Per chunk: stage K -> QK^T -> softmax -> stage Z (same buffer) -> PV.
__global__ __launch_bounds__(256) void k_attn(
    const u16* __restrict__ Qh, const u16* __restrict__ Ql,
    const u16* __restrict__ Kh, const u16* __restrict__ Kl,
    const u16* __restrict__ Zh, const u16* __restrict__ Zl,
    float* __restrict__ Ao)
{
    const int i = blockIdx.x;            // 0..1023
    const int xcd = i & 7;
    const int j = i >> 3;                // 0..127
    const int bh = xcd*8 + (j >> 4);
    const int mt = j & 15;
    const int b = bh >> 3, h = bh & 7;
    const int tid = threadIdx.x;
    const int w = tid >> 6, l = tid & 63, lr = l & 15, lg = l >> 4;
    const int m0 = mt*64 + w*16;         // wave-owned 16 m-rows

    __shared__ u16 bufh[6912], bufl[6912];   // K view: [64][104]; Z view: [96][72]

    f32x4 zero = {0.f, 0.f, 0.f, 0.f};

    // Q B-frags (once; q pre-scaled by ISQ)
    const long qbase = ((long)bh*1024 + m0 + lr)*96 + lg*8;
    bf16x8 qhf[3], qlf[3];
    #pragma unroll
    for (int s = 0; s < 3; ++s) {
        qhf[s] = *(const bf16x8*)(Qh + qbase + s*32);
        qlf[s] = *(const bf16x8*)(Ql + qbase + s*32);
    }

    f32x4 acc2[6];
    #pragma unroll
    for (int f = 0; f < 6; ++f) acc2[f] = zero;
    float run_m = -1e30f, run_l = 0.f;

    const long zrow = (long)(b*768 + h*96);
    const int sAl = lr + ((lg & 1) << 5);
    const int sBl = sAl + 16;
    const bool hiT = (lg & 2) != 0;

    for (int c = 0; c < 16; ++c) {
        const int n0 = c*64;
        __syncthreads();   // previous PV reads done
        // ---- stage K rows n0..n0+63 into buf (K view [nl][104])
        {
            const long kgb = ((long)bh*1024 + n0)*96;
            #pragma unroll
            for (int it = 0; it < 3; ++it) {
                const int id = it*256 + tid;          // 0..767
                const int row = id / 12, off = (id % 12)*8;
                *(u16x8*)&bufh[row*104 + off] = *(const u16x8*)(Kh + kgb + id*8);
                *(u16x8*)&bufl[row*104 + off] = *(const u16x8*)(Kl + kgb + id*8);
            }
        }
        __syncthreads();

        // ---- QK^T: 4 swapped tiles from LDS (lane: m=lr, n = n0 + t*16 + lg*4 + r)
        f32x4 sc[4];
        #pragma unroll
        for (int t = 0; t < 4; ++t) {
            const int krow = (t*16 + lr)*104 + lg*8;
            f32x4 a = zero;
            #pragma unroll
            for (int s = 0; s < 3; ++s) {
                const bf16x8 khf = *(const bf16x8*)&bufh[krow + s*32];
                const bf16x8 klf = *(const bf16x8*)&bufl[krow + s*32];
                a = __builtin_amdgcn_mfma_f32_16x16x32_bf16(khf, qhf[s], a, 0, 0, 0);
                a = __builtin_amdgcn_mfma_f32_16x16x32_bf16(khf, qlf[s], a, 0, 0, 0);
                a = __builtin_amdgcn_mfma_f32_16x16x32_bf16(klf, qhf[s], a, 0, 0, 0);
            }
            sc[t] = a;
        }

        // ---- online softmax update (scores already ISQ-scaled; row m = lr)
        float tmax = -1e30f;
        #pragma unroll
        for (int t = 0; t < 4; ++t)
            #pragma unroll
            for (int r = 0; r < 4; ++r)
                tmax = fmaxf(tmax, sc[t][r]);
        tmax = fmaxf(tmax, __shfl_xor(tmax, 16));
        tmax = fmaxf(tmax, __shfl_xor(tmax, 32));
        const float m_new = fmaxf(run_m, tmax);
        const float fr = __expf(run_m - m_new);
        float sm = 0.f;
        #pragma unroll
        for (int t = 0; t < 4; ++t)
            #pragma unroll
            for (int r = 0; r < 4; ++r) {
                const float p = __expf(sc[t][r] - m_new);
                sc[t][r] = p;
                sm += p;
            }
        sm += __shfl_xor(sm, 16);
        sm += __shfl_xor(sm, 32);
        run_l = run_l * fr + sm;
        run_m = m_new;
        #pragma unroll
        for (int r = 0; r < 4; ++r) {
            const float fm = __shfl(fr, lg*4 + r);
            #pragma unroll
            for (int ff = 0; ff < 6; ++ff) acc2[ff][r] *= fm;
        }

        __syncthreads();   // QK^T reads done; buffer free for Z
        // ---- stage Z (96 rows x 64 cols) into buf (Z view [f][72])
        {
            #pragma unroll
            for (int it = 0; it < 3; ++it) {
                const int id = it*256 + tid;          // 0..767
                const int f = id >> 3, off = (id & 7)*8;
                const long zg = (zrow + f)*1024 + n0 + off;
                *(u16x8*)&bufh[f*72 + off] = *(const u16x8*)(Zh + zg);
                *(u16x8*)&bufl[f*72 + off] = *(const u16x8*)(Zl + zg);
            }
        }
        __syncthreads();

        // ---- PV: 2 kb of 32 n; P via shfl exchange into K=32 A-frags
        #pragma unroll
        for (int kb = 0; kb < 2; ++kb) {
            const f32x4 pA = sc[2*kb], pB = sc[2*kb + 1];
            const u16 a0 = f2bf(pA[0]), a1 = f2bf(pA[1]), a2 = f2bf(pA[2]), a3 = f2bf(pA[3]);
            const u16 b0 = f2bf(pB[0]), b1 = f2bf(pB[1]), b2 = f2bf(pB[2]), b3 = f2bf(pB[3]);
            const unsigned ah01 = (unsigned)a0 | ((unsigned)a1 << 16);
            const unsigned ah23 = (unsigned)a2 | ((unsigned)a3 << 16);
            const unsigned bh01 = (unsigned)b0 | ((unsigned)b1 << 16);
            const unsigned bh23 = (unsigned)b2 | ((unsigned)b3 << 16);
            const unsigned al01 = (unsigned)f2bf(pA[0]-bf2f(a0)) | ((unsigned)f2bf(pA[1]-bf2f(a1)) << 16);
            const unsigned al23 = (unsigned)f2bf(pA[2]-bf2f(a2)) | ((unsigned)f2bf(pA[3]-bf2f(a3)) << 16);
            const unsigned bl01 = (unsigned)f2bf(pB[0]-bf2f(b0)) | ((unsigned)f2bf(pB[1]-bf2f(b1)) << 16);
            const unsigned bl23 = (unsigned)f2bf(pB[2]-bf2f(b2)) | ((unsigned)f2bf(pB[3]-bf2f(b3)) << 16);

            const unsigned hA01 = (unsigned)__shfl((int)ah01, sAl), hB01 = (unsigned)__shfl((int)bh01, sAl);
            const unsigned hA23 = (unsigned)__shfl((int)ah23, sAl), hB23 = (unsigned)__shfl((int)bh23, sAl);
            const unsigned hA45 = (unsigned)__shfl((int)ah01, sBl), hB45 = (unsigned)__shfl((int)bh01, sBl);
            const unsigned hA67 = (unsigned)__shfl((int)ah23, sBl), hB67 = (unsigned)__shfl((int)bh23, sBl);
            const unsigned lA01 = (unsigned)__shfl((int)al01, sAl), lB01 = (unsigned)__shfl((int)bl01, sAl);
            const unsigned lA23 = (unsigned)__shfl((int)al23, sAl), lB23 = (unsigned)__shfl((int)bl23, sAl);
            const unsigned lA45 = (unsigned)__shfl((int)al01, sBl), lB45 = (unsigned)__shfl((int)bl01, sBl);
            const unsigned lA67 = (unsigned)__shfl((int)al23, sBl), lB67 = (unsigned)__shfl((int)bl23, sBl);

            const u32x4 th = { hiT ? hB01 : hA01, hiT ? hB23 : hA23,
                               hiT ? hB45 : hA45, hiT ? hB67 : hA67 };
            const u32x4 tl = { hiT ? lB01 : lA01, hiT ? lB23 : lA23,
                               hiT ? lB45 : lA45, hiT ? lB67 : lA67 };
            const bf16x8 pah = __builtin_bit_cast(bf16x8, th);
            const bf16x8 pal = __builtin_bit_cast(bf16x8, tl);

            #pragma unroll
            for (int ff = 0; ff < 6; ++ff) {
                const int zoff = (ff*16 + lr)*72 + kb*32 + lg*8;
                const bf16x8 zh8 = *(const bf16x8*)&bufh[zoff];
                const bf16x8 zl8 = *(const bf16x8*)&bufl[zoff];
                acc2[ff] = __builtin_amdgcn_mfma_f32_16x16x32_bf16(pah, zh8, acc2[ff], 0, 0, 0);
                acc2[ff] = __builtin_amdgcn_mfma_f32_16x16x32_bf16(pah, zl8, acc2[ff], 0, 0, 0);
                acc2[ff] = __builtin_amdgcn_mfma_f32_16x16x32_bf16(pal, zh8, acc2[ff], 0, 0, 0);
            }
        }
    }

    // ---- normalize and write (O[m = lg*4+r][f = ff*16+lr] -> Ao[f][m], float4 over r)
    const float lrec = 1.0f / run_l;
    #pragma unroll
    for (int r = 0; r < 4; ++r) {
        const float iv = __shfl(lrec, lg*4 + r);
        #pragma unroll
        for (int ff = 0; ff < 6; ++ff) acc2[ff][r] *= iv;
    }
    #pragma unroll
    for (int ff = 0; ff < 6; ++ff) {
        float4 o;
        o.x = acc2[ff][0]; o.y = acc2[ff][1]; o.z = acc2[ff][2]; o.w = acc2[ff][3];
        *(float4*)&Ao[(zrow + ff*16 + lr)*1024 + m0 + lg*4] = o;
    }
}

// ---------------------------------------------------------------- VN LayerNorm (+residual) [r1 verbatim]
__global__ __launch_bounds__(256) void k_vnln(
    const float* __restrict__ X, const float* __restrict__ Res,
    const float* __restrict__ g, const float* __restrict__ be,
    float* __restrict__ Out)
{
    const int b  = blockIdx.x >> 5;
    const int n  = ((blockIdx.x & 31) << 5) + threadIdx.x;
    const int ty = threadIdx.y;
    const long bbase = (long)b * (256*3*1024);
    float sum = 0.0f, sq = 0.0f;
    for (int ci = 0; ci < 32; ++ci) {
        const int c = (ty << 5) + ci;
        const long base = bbase + (long)c*3072 + n;
        const float x0 = X[base], x1 = X[base+1024], x2 = X[base+2048];
        const float nr = sqrtf(x0*x0 + x1*x1 + x2*x2) + VN_EPS;
        sum += nr; sq += nr*nr;
    }
    __shared__ float s_sum[8][32], s_sq[8][32];
    s_sum[ty][threadIdx.x] = sum; s_sq[ty][threadIdx.x] = sq;
    __syncthreads();
    __shared__ float s_mu[32], s_rs[32];
    if (ty == 0) {
        float S = 0.0f, Q = 0.0f;
        #pragma unroll
        for (int w = 0; w < 8; ++w) { S += s_sum[w][threadIdx.x]; Q += s_sq[w][threadIdx.x]; }
        const float mu = S / 256.0f;
        s_mu[threadIdx.x] = mu;
        s_rs[threadIdx.x] = rsqrtf(Q / 256.0f - mu*mu + LN_EPS);
    }
    __syncthreads();
    const float mu = s_mu[threadIdx.x], rstd = s_rs[threadIdx.x];
    for (int ci = 0; ci < 32; ++ci) {
        const int c = (ty << 5) + ci;
        const long base = bbase + (long)c*3072 + n;
        const float x0 = X[base], x1 = X[base+1024], x2 = X[base+2048];
        const float nr = sqrtf(x0*x0 + x1*x1 + x2*x2) + VN_EPS;
        const float ln = (nr - mu) * rstd * g[c] + be[c];
        const float s  = ln / nr;
        float o0 = x0*s, o1 = x1*s, o2 = x2*s;
        if (Res) { o0 += Res[base]; o1 += Res[base+1024]; o2 += Res[base+2048]; }
        Out[base] = o0; Out[base+1024] = o1; Out[base+2048] = o2;
    }
}

// ---------------------------------------------------------------- BN stats [r7 verbatim]
__global__ __launch_bounds__(256) void k_bnstats(
    const float* __restrict__ X, float* __restrict__ bnst)
{
    const int c = blockIdx.x;
    const int t = threadIdx.x;
    float sum = 0.0f, sq = 0.0f;
    for (int b = 0; b < 8; ++b) {
        const long rowbase = ((long)(b*256 + c)) * 3072;
        for (int n0 = 0; n0 < 1024; n0 += 256) {
            const int n = n0 + t;
            const float x0 = X[rowbase + n], x1 = X[rowbase + 1024 + n], x2 = X[rowbase + 2048 + n];
            const float nr = sqrtf(x0*x0 + x1*x1 + x2*x2) + VN_EPS;
            sum += nr; sq += nr*nr;
        }
    }
    #pragma unroll
    for (int off = 32; off > 0; off >>= 1) {
        sum += __shfl_xor(sum, off);
        sq  += __shfl_xor(sq,  off);
    }
    __shared__ float rs[4], rq[4];
    if ((t & 63) == 0) { rs[t >> 6] = sum; rq[t >> 6] = sq; }
    __syncthreads();
    if (t == 0) {
        const float S = rs[0]+rs[1]+rs[2]+rs[3];
        const float Q = rq[0]+rq[1]+rq[2]+rq[3];
        const float mu = S / 8192.0f;
        bnst[c] = mu;
        bnst[256 + c] = rsqrtf(Q / 8192.0f - mu*mu + BN_EPS);
    }
}

// ---------------------------------------------------------------- BN apply in place [r7 verbatim]
__global__ __launch_bounds__(256) void k_bnapply(
    float* __restrict__ X, const float* __restrict__ bnst,
    const float* __restrict__ g, const float* __restrict__ be)
{
    const long i = (long)blockIdx.x * 256 + threadIdx.x;
    const int  n  = (int)(i & 1023);
    const long bc = i >> 10;
    const int  c  = (int)(bc & 255);
    const long base = bc * 3072 + n;
    const float x0 = X[base], x1 = X[base+1024], x2 = X[base+2048];
    const float nr = sqrtf(x0*x0 + x1*x1 + x2*x2) + VN_EPS;
    const float bn = (nr - bnst[c]) * bnst[256 + c] * g[c] + be[c];
    const float s  = bn / nr;
    X[base]      = x0*s;
    X[base+1024] = x1*s;
    X[base+2048] = x2*s;
}

// ---------------------------------------------------------------- VN leaky relu (slope 0) in place [r7 verbatim]
__global__ __launch_bounds__(256) void k_leaky(
    float* __restrict__ X, const float* __restrict__ Dd)
{
    const long i = (long)blockIdx.x * 256 + threadIdx.x;
    const long base = (i >> 10) * 3072 + (i & 1023);
    const float x0 = X[base], x1 = X[base+1024], x2 = X[base+2048];
    const float d0 = Dd[base], d1 = Dd[base+1024], d2 = Dd[base+2048];
    const float dot = x0*d0 + x1*d1 + x2*d2;
    if (dot < 0.0f) {
        const float f = dot / (d0*d0 + d1*d1 + d2*d2 + VN_EPS);
        X[base]      = x0 - f*d0;
        X[base+1024] = x1 - f*d1;
        X[base+2048] = x2 - f*d2;
    }
}

// ================================================================ launch
extern "C" void kernel_launch(void* const* d_in, const int* in_sizes, int n_in,
                              void* d_out, int out_size, void* d_ws, size_t ws_size,
                              hipStream_t stream)
{
    const float* x    = (const float*)d_in[0];
    const float* Wq   = (const float*)d_in[1];
    const float* bq   = (const float*)d_in[2];
    const float* Wk   = (const float*)d_in[3];
    const float* bk   = (const float*)d_in[4];
    const float* Wz   = (const float*)d_in[5];
    const float* bz   = (const float*)d_in[6];
    const float* Wo   = (const float*)d_in[7];
    const float* bo   = (const float*)d_in[8];
    const float* ln1g = (const float*)d_in[9];
    const float* ln1b = (const float*)d_in[10];
    const float* Wm1  = (const float*)d_in[11];
    const float* bm1  = (const float*)d_in[12];
    const float* bng  = (const float*)d_in[13];
    const float* bnb  = (const float*)d_in[14];
    const float* Wr   = (const float*)d_in[15];
    const float* Wm2  = (const float*)d_in[16];
    const float* bm2  = (const float*)d_in[17];
    const float* ln2g = (const float*)d_in[18];
    const float* ln2b = (const float*)d_in[19];
    float* out = (float*)d_out;

    char* wsb = (char*)d_ws;
    u16*   qh  = (u16*)(wsb + 0);
    u16*   ql  = (u16*)(wsb + 12582912);
    u16*   kh  = (u16*)(wsb + 25165824);
    u16*   kl  = (u16*)(wsb + 37748736);
    u16*   zh  = (u16*)(wsb + 50331648);
    u16*   zl  = (u16*)(wsb + 62914560);
    u16*   wth = (u16*)(wsb + 109051904);
    u16*   wtl = (u16*)(wsb + 109969408);
    float* uall= (float*)(wsb + 110886912);
    float* bnst= (float*)(wsb + 110905344);
    // phase C aliases (attention buffers dead)
    float* ao  = out;                          // d_out as attn-out scratch
    float* y0f = (float*)(wsb + 0);
    float* y   = (float*)(wsb + 25165824);
    float* h   = (float*)(wsb + 50331648);
    float* dv  = (float*)(wsb + 75497472);
    float* h2  = (float*)(wsb + 0);

    const dim3 GC(16, 4, 24);

    k_u<<<6, 256, 0, stream>>>(bq, bk, bz, bo, bm1, bm2, uall);
    k_wtrans<<<dim3(4,4,7), 256, 0, stream>>>(Wq, Wk, Wz, Wo, Wm1, Wr, Wm2, wth, wtl);

    // projections (q pre-scaled by ISQ)
    k_cgemm<2><<<GC, 256, 0, stream>>>(x, wth + 0*65536, wtl + 0*65536, uall + 0*768, nullptr, qh, ql, ISQ);
    k_cgemm<2><<<GC, 256, 0, stream>>>(x, wth + 1*65536, wtl + 1*65536, uall + 1*768, nullptr, kh, kl, 1.0f);
    k_cgemm<1><<<GC, 256, 0, stream>>>(x, wth + 2*65536, wtl + 2*65536, uall + 2*768, nullptr, zh, zl, 1.0f);

    // fused attention (time-shared LDS K/Z buffer, XCD-swizzled)
    k_attn<<<1024, 256, 0, stream>>>(qh, ql, kh, kl, zh, zl, ao);

    // out projection + LN1 (+ residual x)
    k_cgemm<0><<<GC, 256, 0, stream>>>(ao, wth + 3*65536, wtl + 3*65536, uall + 3*768, y0f, nullptr, nullptr, 1.0f);
    k_vnln<<<256, dim3(32,8), 0, stream>>>(y0f, x, ln1g, ln1b, y);

    // MLP
    k_cgemm<0><<<GC, 256, 0, stream>>>(y, wth + 4*65536, wtl + 4*65536, uall + 4*768, h, nullptr, nullptr, 1.0f);
    k_bnstats<<<256, 256, 0, stream>>>(h, bnst);
    k_bnapply<<<8192, 256, 0, stream>>>(h, bnst, bng, bnb);
    k_cgemm<0><<<GC, 256, 0, stream>>>(h, wth + 5*65536, wtl + 5*65536, (const float*)nullptr, dv, nullptr, nullptr, 1.0f);
    k_leaky<<<8192, 256, 0, stream>>>(h, dv);
    k_cgemm<0><<<GC, 256, 0, stream>>>(h, wth + 6*65536, wtl + 6*65536, uall + 5*768, h2, nullptr, nullptr, 1.0f);
    k_vnln<<<256, dim3(32,8), 0, stream>>>(h2, y, ln2g, ln2b, out);
}